// Round 2
// baseline (67.053 us; speedup 1.0000x reference)
//
#include <hip/hip_runtime.h>

// Problem constants (reference: B=64, T=4096, H=512)
#define T_LEN 4096
#define H_LEN 512
#define B_LEN 64
#define TCH   32              // t's per chunk block
#define NCHUNK (T_LEN / TCH)  // 128 chunk blocks

// Closed form of the diagonal linear scan:
//   z[bi] = sum_t x[bi,t]*g[t] + K
//   g[t]  = sum_j w_j b_j a_j^{T-1-t}
//   K     = sum_j w_j c_j (1-a_j^T)/(1-a_j) + e
//
// TWO dispatches, ZERO atomics, zero fences (round-1 decisive experiment:
// the single-dispatch version funneled 8192 device-scope atomicAdds onto 4
// cache lines from 8 XCDs — this removes that serialization entirely):
//   kernel 1 (128 blocks): g[t] for its 32-wide t-chunk -> d_ws (plain
//                          coalesced stores; 2M exp2f total, no redundancy).
//   kernel 2 (64 blocks) : block = output row. Full 4096-dot x[row,:] . g
//                          (float4, coalesced) + fp64 K-series (redundant
//                          per block, 2 j's/thread, 12 exact squarings; the
//                          1/(1-a) amplification up to 1000x demands fp64),
//                          block-reduce, ONE plain store z[row]. Full
//                          overwrite -> no reliance on output poison value.
// Cross-kernel g visibility is guaranteed by stream order (kernel-boundary
// release/acquire in the HIP memory model) — no user fences, which a prior
// session measured at ~42us in L2 drains. d_ws is re-poisoned each
// iteration by the harness (the 40us 256MB fill in rocprof); we overwrite
// g before reading it, so that's benign.
__global__ __launch_bounds__(256) void g_kernel(
    const float* __restrict__ a,
    const float* __restrict__ b,
    const float* __restrict__ w,
    float* __restrict__ g)         // [T_LEN] in d_ws
{
    const int tid = threadIdx.x;
    const int blk = blockIdx.x;

    __shared__ float wb[H_LEN];
    __shared__ float l2a[H_LEN];
    for (int j = tid; j < H_LEN; j += 256) {
        wb[j]  = w[j] * b[j];
        l2a[j] = log2f(a[j]);
    }
    __syncthreads();

    const int   tt = tid & 31;          // t within chunk
    const int   jg = tid >> 5;          // 8 j-groups x 64 j's each
    const float k  = (float)(T_LEN - 1 - (blk * TCH + tt));
    const int   j0 = jg * (H_LEN / 8);
    float s = 0.f;
#pragma unroll 8
    for (int jj = 0; jj < H_LEN / 8; ++jj) {
        const int j = j0 + jj;
        s += wb[j] * exp2f(k * l2a[j]); // 32-lane-uniform LDS reads: broadcast
    }
    __shared__ float part[8][TCH];
    part[jg][tt] = s;                   // word addr = tid: conflict-free
    __syncthreads();
    if (tid < TCH) {
        float acc = 0.f;
#pragma unroll
        for (int g2 = 0; g2 < 8; ++g2) acc += part[g2][tid];
        g[blk * TCH + tid] = acc;       // 32 consecutive floats: coalesced
    }
}

__global__ __launch_bounds__(256) void dot_kernel(
    const float* __restrict__ x,   // [B_LEN, T_LEN]
    const float* __restrict__ a,
    const float* __restrict__ c,
    const float* __restrict__ w,
    const float* __restrict__ e,
    const float* __restrict__ g,   // [T_LEN] in d_ws
    float* __restrict__ z)         // [B_LEN] (fully overwritten)
{
    const int tid = threadIdx.x;
    const int row = blockIdx.x;
    const float* xr = x + (size_t)row * T_LEN;

    // --- dot(x[row,:], g): 16 elems/thread as 4x float4, coalesced ---
    float local = 0.f;
#pragma unroll 4
    for (int seg = 0; seg < 4; ++seg) {
        const int idx = seg * 1024 + tid * 4;
        const float4 xv = *(const float4*)(xr + idx);
        const float4 gv = *(const float4*)(g + idx);
        local += xv.x * gv.x + xv.y * gv.y + xv.z * gv.z + xv.w * gv.w;
    }

    // --- K partial: 2 j's per thread, fp64 exact squarings for a^4096 ---
    double kacc = 0.0;
#pragma unroll 2
    for (int jj = 0; jj < 2; ++jj) {
        const int j = tid + jj * 256;
        const double aj = (double)a[j];
        double p = aj;
#pragma unroll
        for (int i = 0; i < 12; ++i) p *= p;   // a^4096
        kacc += (double)w[j] * (double)c[j] * (1.0 - p) / (1.0 - aj);
    }
    local += (float)kacc;
    if (tid == 0) local += e[0];

    // --- block reduce 256 -> 1: wave butterfly + 4-way LDS fold ---
    local += __shfl_xor(local, 1, 64);
    local += __shfl_xor(local, 2, 64);
    local += __shfl_xor(local, 4, 64);
    local += __shfl_xor(local, 8, 64);
    local += __shfl_xor(local, 16, 64);
    local += __shfl_xor(local, 32, 64);
    __shared__ float wsum[4];
    if ((tid & 63) == 0) wsum[tid >> 6] = local;
    __syncthreads();
    if (tid == 0) z[row] = wsum[0] + wsum[1] + wsum[2] + wsum[3];
}

extern "C" void kernel_launch(void* const* d_in, const int* in_sizes, int n_in,
                              void* d_out, int out_size, void* d_ws, size_t ws_size,
                              hipStream_t stream) {
    const float* x = (const float*)d_in[0];  // [B,T]
    const float* a = (const float*)d_in[1];  // [H]
    const float* b = (const float*)d_in[2];  // [H]
    const float* c = (const float*)d_in[3];  // [H]
    const float* w = (const float*)d_in[4];  // [H]
    const float* e = (const float*)d_in[5];  // [1]
    float* out = (float*)d_out;              // [B] fp32
    float* g   = (float*)d_ws;               // [T_LEN] scratch (16 KB)

    g_kernel<<<NCHUNK, 256, 0, stream>>>(a, b, w, g);
    dot_kernel<<<B_LEN, 256, 0, stream>>>(x, a, c, w, e, g, out);
}